// Round 4
// baseline (334.376 us; speedup 1.0000x reference)
//
#include <hip/hip_runtime.h>
#include <hip/hip_bf16.h>

#define TT 128
#define BB 512
#define DD 500
#define NVOCAB 1000
#define NV4 125   // DD floats = 125 float4 per row (2000 B, 16B-aligned)

typedef float vfloat4 __attribute__((ext_vector_type(4)));  // native vec: OK for nontemporal builtins

// ---------------------------------------------------------------------------
// Workspace layout (16B-aligned base):
//   mask    : ulonglong2[BB]   128-bit valid mask per column      8 KB
//   new_len : int[BB]                                             2 KB
//   order   : int[BB]                                             2 KB
//   lohi    : ushort[TT*BB]    lo | hi<<7 per segment           128 KB
// ---------------------------------------------------------------------------

// Kernel 1: per-column greedy packer metadata. 8 blocks x 64 threads.
__global__ void __launch_bounds__(64)
meta_kernel(const int* __restrict__ src,
            const int* __restrict__ token_lengths,
            const int* __restrict__ token_len_p,
            unsigned short* __restrict__ lohi,
            int* __restrict__ new_len,
            ulonglong2* __restrict__ mask) {
    __shared__ int tl[NVOCAB];
    __shared__ int ssrc[TT * 64];

    int tid = threadIdx.x;
    for (int i = tid; i < NVOCAB; i += 64) tl[i] = token_lengths[i];

    int b = blockIdx.x * 64 + tid;
    #pragma unroll 8
    for (int t = 0; t < TT; ++t) ssrc[t * 64 + tid] = src[t * BB + b];
    __syncthreads();

    int bits = token_len_p[0];
    int token_len = bits;
    if (bits > 1000000 || bits <= 0) token_len = (int)__int_as_float(bits);

    int curr = 0, seg = 0, lo = 0, pend = -1;
    unsigned long long m0 = 0ull, m1 = 0ull;
    for (int t = 0; t < TT; ++t) {
        int s = ssrc[t * 64 + tid];
        if (s == 1) continue;                  // pad: invalid
        int l = (s == 0) ? 4 : tl[s];
        if (pend >= 0 && curr + l > token_len) {
            lohi[seg * BB + b] = (unsigned short)(lo | (pend << 7));
            lo = pend + 1; curr = 0; seg++;
        }
        curr += l; pend = t;
        if (t < 64) m0 |= 1ull << t; else m1 |= 1ull << (t - 64);
    }
    if (pend >= 0) {
        lohi[seg * BB + b] = (unsigned short)(lo | (pend << 7));
        seg++;
    }
    new_len[b] = seg;
    mask[b] = make_ulonglong2(m0, m1);
}

// Kernel 2: stable descending argsort via rank-count; order + lengths only.
__global__ void __launch_bounds__(BB)
sort_kernel(const int* __restrict__ new_len,
            int* __restrict__ order,
            float* __restrict__ out_len) {
    __shared__ int lens[BB];
    __shared__ int ord[BB];
    int j = threadIdx.x;
    lens[j] = new_len[j];
    __syncthreads();
    int lj = lens[j];
    int rank = 0;
    #pragma unroll 8
    for (int i = 0; i < BB; ++i) {
        int li = lens[i];
        rank += (int)((li > lj) || (li == lj && i < j));
    }
    ord[rank] = j;
    __syncthreads();
    int b = ord[j];
    order[j] = b;
    out_len[j] = (float)lens[b];
}

// Kernel 3: gather with explicit MLP.
// 256 threads per block handle 16 consecutive output rows (r uniform, j
// consecutive). Each 128-lane half owns 8 rows:
//   phase A: issue ALL identity-row loads back-to-back (MLP=8)
//   phase B: packed rows: 4-wide unrolled mask-weighted FMA sum (MLP=4)
//   phase C: non-temporal stores of identity rows (out is never re-read)
__global__ void __launch_bounds__(256)
gather_kernel(const float* __restrict__ emb,
              const int* __restrict__ order,
              const int* __restrict__ new_len,
              const unsigned short* __restrict__ lohi,
              const ulonglong2* __restrict__ mask,
              float* __restrict__ out) {
    __shared__ int sb[16];
    __shared__ int sn[16];
    __shared__ int slh[16];
    __shared__ unsigned long long smx[16], smy[16];

    int tid  = threadIdx.x;
    int half = tid >> 7;          // 0 or 1
    int lane = tid & 127;
    int row0 = blockIdx.x * 16;   // 16-aligned -> r uniform over the block
    int r    = row0 >> 9;
    int j0   = row0 & 511;

    if (tid < 16) {
        int j = j0 + tid;
        int b = order[j];
        int n = new_len[b];
        sb[tid] = b;
        sn[tid] = n;
        slh[tid] = (r < n) ? (int)lohi[r * BB + b] : 0;
        ulonglong2 m = mask[b];
        smx[tid] = m.x; smy[tid] = m.y;
    }
    __syncthreads();

    bool act = (lane < NV4);

    // ---- phase A: identity-row loads, all independent ----
    vfloat4 v[8];
    bool iden[8];
    #pragma unroll
    for (int k = 0; k < 8; ++k) {
        int kk = half * 8 + k;
        iden[k] = (r >= sn[kk]);
        if (iden[k] && act)
            v[k] = *((const vfloat4*)(emb + ((size_t)r * BB + sb[kk]) * DD) + lane);
    }

    // ---- phase B: packed rows, unroll-4 grouped loads ----
    #pragma unroll
    for (int k = 0; k < 8; ++k) {
        if (iden[k]) continue;
        int kk = half * 8 + k;
        int b  = sb[kk];
        int lh = slh[kk];
        int lo = lh & 127;
        int hi = (lh >> 7) & 127;
        unsigned long long mx = smx[kk], my = smy[kk];
        vfloat4 acc = (vfloat4)(0.f);
        for (int t = lo; t <= hi; t += 4) {
            vfloat4 vv[4];
            float   w[4];
            #pragma unroll
            for (int i = 0; i < 4; ++i) {
                int ti = t + i; if (ti > hi) ti = hi;
                unsigned long long bit = (ti < 64) ? (mx >> ti) : (my >> (ti - 64));
                w[i] = (t + i <= hi) ? (float)(bit & 1ull) : 0.f;
                if (act)
                    vv[i] = *((const vfloat4*)(emb + ((size_t)ti * BB + b) * DD) + lane);
            }
            if (act) {
                #pragma unroll
                for (int i = 0; i < 4; ++i) {
                    acc.x = fmaf(w[i], vv[i].x, acc.x);
                    acc.y = fmaf(w[i], vv[i].y, acc.y);
                    acc.z = fmaf(w[i], vv[i].z, acc.z);
                    acc.w = fmaf(w[i], vv[i].w, acc.w);
                }
            }
        }
        if (act)
            __builtin_nontemporal_store(acc,
                (vfloat4*)(out + (size_t)(row0 + kk) * DD) + lane);
    }

    // ---- phase C: identity-row stores ----
    #pragma unroll
    for (int k = 0; k < 8; ++k) {
        int kk = half * 8 + k;
        if (iden[k] && act)
            __builtin_nontemporal_store(v[k],
                (vfloat4*)(out + (size_t)(row0 + kk) * DD) + lane);
    }
}

extern "C" void kernel_launch(void* const* d_in, const int* in_sizes, int n_in,
                              void* d_out, int out_size, void* d_ws, size_t ws_size,
                              hipStream_t stream) {
    const float* embedded      = (const float*)d_in[0];
    const int*   src           = (const int*)d_in[1];
    // d_in[2] = lengths (unused by reference computation)
    const int*   token_lengths = (const int*)d_in[3];
    const int*   token_len_p   = (const int*)d_in[4];

    float* out = (float*)d_out;                 // T*B*D packed rows + B lengths

    ulonglong2*     mask    = (ulonglong2*)d_ws;                 // 8 KB
    int*            new_len = (int*)(mask + BB);                 // 2 KB
    int*            order   = new_len + BB;                      // 2 KB
    unsigned short* lohi    = (unsigned short*)(order + BB);     // 128 KB

    meta_kernel<<<BB / 64, 64, 0, stream>>>(src, token_lengths, token_len_p,
                                            lohi, new_len, mask);
    sort_kernel<<<1, BB, 0, stream>>>(new_len, order,
                                      out + (size_t)TT * BB * DD);
    gather_kernel<<<TT * BB / 16, 256, 0, stream>>>(embedded, order, new_len,
                                                    lohi, mask, out);
}